// Round 3
// baseline (100.361 us; speedup 1.0000x reference)
//
#include <hip/hip_runtime.h>
#include <math.h>
#include <float.h>

// Problem constants (from the reference)
#define NN 4096
#define DD 512
#define PP 8
#define QQ 32
#define NB_TOT (PP + QQ)          // 40 neighbors per anchor
#define NWAVES 5                  // 5 waves x 8 groups = 40 neighbors
constexpr float MARGIN = 1.0f;
constexpr float L2W    = 0.005f;
constexpr float EPS    = 1e-6f;

__device__ inline float wave_reduce_sum(float v) {
    v += __shfl_xor(v, 32, 64);
    v += __shfl_xor(v, 16, 64);
    v += __shfl_xor(v,  8, 64);
    v += __shfl_xor(v,  4, 64);
    v += __shfl_xor(v,  2, 64);
    v += __shfl_xor(v,  1, 64);
    return v;
}

__device__ inline float wave_reduce_max(float v) {
    v = fmaxf(v, __shfl_xor(v, 32, 64));
    v = fmaxf(v, __shfl_xor(v, 16, 64));
    v = fmaxf(v, __shfl_xor(v,  8, 64));
    v = fmaxf(v, __shfl_xor(v,  4, 64));
    v = fmaxf(v, __shfl_xor(v,  2, 64));
    v = fmaxf(v, __shfl_xor(v,  1, 64));
    return v;
}

// 3-step reduce within each 8-lane group (masks < 8 stay in-group)
__device__ inline float group8_reduce_sum(float v) {
    v += __shfl_xor(v, 1, 64);
    v += __shfl_xor(v, 2, 64);
    v += __shfl_xor(v, 4, 64);
    return v;
}

// One block per anchor; 5 waves x 8 groups; each 8-lane group owns ONE
// neighbor row (64 elems/lane accumulated in-register -> only a 3-step
// cross-lane reduce). 16 independent dwordx4 loads in flight per lane.
__global__ __launch_bounds__(320) void dist_kernel(
    const float* __restrict__ batch,
    const int*   __restrict__ anchors,
    const int*   __restrict__ pos_idx,
    const int*   __restrict__ neg_idx,
    float*       __restrict__ ws)
{
    const int i    = blockIdx.x;
    const int tid  = threadIdx.x;
    const int lane = tid & 63;
    const int wave = tid >> 6;       // 0..4
    const int g    = lane >> 3;      // group 0..7
    const int k    = lane & 7;       // lane-in-group

    __shared__ float dist[NB_TOT];
    __shared__ float norm_sh;

    // ---- anchor fragment: 16 float4 at elems c*32 + k*4 (same for all groups) ----
    const int arow = anchors[i];
    const float* __restrict__ ap = batch + (size_t)arow * DD + k * 4;
    float4 a[16];
    #pragma unroll
    for (int c = 0; c < 16; ++c)
        a[c] = *reinterpret_cast<const float4*>(ap + c * 32);
    #pragma unroll
    for (int c = 0; c < 16; ++c) {   // fold +EPS into the anchor once
        a[c].x += EPS; a[c].y += EPS; a[c].z += EPS; a[c].w += EPS;
    }

    // ---- wave 0 also computes ||batch[i]|| (cheap: 2 loads + 6-step reduce) ----
    if (wave == 0) {
        const float* __restrict__ rp = batch + (size_t)i * DD + lane * 8;
        const float4 r0 = *reinterpret_cast<const float4*>(rp);
        const float4 r1 = *reinterpret_cast<const float4*>(rp + 4);
        float s = r0.x*r0.x + r0.y*r0.y + r0.z*r0.z + r0.w*r0.w
                + r1.x*r1.x + r1.y*r1.y + r1.z*r1.z + r1.w*r1.w;
        s = wave_reduce_sum(s);
        if (lane == 0) norm_sh = sqrtf(s);
    }

    // ---- this group's neighbor ----
    const int j    = wave * 8 + g;                 // 0..39
    const int nidx = (j < PP) ? pos_idx[i * PP + j]
                              : neg_idx[i * QQ + (j - PP)];

    // ---- issue all 16 row loads (independent -> all in flight) ----
    const float* __restrict__ bp = batch + (size_t)nidx * DD + k * 4;
    float4 b[16];
    #pragma unroll
    for (int c = 0; c < 16; ++c)
        b[c] = *reinterpret_cast<const float4*>(bp + c * 32);

    // ---- in-register accumulation: 64 elems, 2 VALU each ----
    float acc = 0.0f;
    #pragma unroll
    for (int c = 0; c < 16; ++c) {
        float d;
        d = a[c].x - b[c].x; acc = fmaf(d, d, acc);
        d = a[c].y - b[c].y; acc = fmaf(d, d, acc);
        d = a[c].z - b[c].z; acc = fmaf(d, d, acc);
        d = a[c].w - b[c].w; acc = fmaf(d, d, acc);
    }

    // ---- 3-step in-group reduce, one sqrt per group ----
    acc = group8_reduce_sum(acc);
    if (k == 0) dist[j] = sqrtf(acc);

    __syncthreads();

    // ---- wave-parallel logsumexp epilogue (lanes 0..39 of wave 0) ----
    if (wave == 0) {
        const float d = (lane < NB_TOT) ? dist[lane] : 0.0f;

        const bool pact = (lane < PP);
        const float pm = wave_reduce_max(pact ? d : -FLT_MAX);
        const float ps = wave_reduce_sum(pact ? expf(d - pm) : 0.0f);
        const float pos_term = pm + logf(ps);

        const bool nact = (lane >= PP) && (lane < NB_TOT);
        const float nv = MARGIN - d;
        const float nm = wave_reduce_max(nact ? nv : -FLT_MAX);
        const float ns = wave_reduce_sum(nact ? expf(nv - nm) : 0.0f);
        const float neg_term = nm + logf(ns);

        if (lane == 0)
            ws[i] = fmaxf(0.0f, pos_term + neg_term) + L2W * norm_sh;
    }
}

// Single-block final reduction: out = mean(ws[0..N))
__global__ __launch_bounds__(256) void reduce_kernel(
    const float* __restrict__ ws, float* __restrict__ out)
{
    const int tid  = threadIdx.x;
    const int lane = tid & 63;
    const int wave = tid >> 6;

    const float4* __restrict__ w4 = reinterpret_cast<const float4*>(ws);
    float s = 0.0f;
    #pragma unroll
    for (int k = 0; k < 4; ++k) {          // 1024 float4 total
        const float4 v = w4[tid + 256 * k];
        s += v.x + v.y + v.z + v.w;
    }
    s = wave_reduce_sum(s);

    __shared__ float part[4];
    if (lane == 0) part[wave] = s;
    __syncthreads();
    if (tid == 0)
        out[0] = (part[0] + part[1] + part[2] + part[3]) * (1.0f / (float)NN);
}

extern "C" void kernel_launch(void* const* d_in, const int* in_sizes, int n_in,
                              void* d_out, int out_size, void* d_ws, size_t ws_size,
                              hipStream_t stream) {
    const float* batch   = (const float*)d_in[0];
    const int*   anchors = (const int*)d_in[1];
    const int*   pos_idx = (const int*)d_in[2];
    const int*   neg_idx = (const int*)d_in[3];
    float*       ws      = (float*)d_ws;
    float*       out     = (float*)d_out;

    dist_kernel<<<NN, 320, 0, stream>>>(batch, anchors, pos_idx, neg_idx, ws);
    reduce_kernel<<<1, 256, 0, stream>>>(ws, out);
}